// Round 6
// baseline (584.196 us; speedup 1.0000x reference)
//
#include <hip/hip_runtime.h>

#define TPB 256
#define BEB 2048  // edges per bucket block (LDS-staged)
#define SEB 2048  // edges per scatter2/hist block

// ---------- index-width detect + zero chunk counters ----------
__global__ void k_detect_i64(const unsigned int* __restrict__ ei, int E,
                             int* __restrict__ flag, int* __restrict__ ccnt) {
  __shared__ int nz;
  if (threadIdx.x == 0) nz = 0;
  if (threadIdx.x < 8) ccnt[threadIdx.x] = 0;
  __syncthreads();
  int step = E / 4096;
  if (step < 1) step = 1;
  for (int t = threadIdx.x; t < 4096; t += blockDim.x) {
    long long pos = 1 + 2LL * (long long)t * step;   // odd dword positions
    if (pos < 2LL * (long long)E && ei[pos] != 0u) atomicAdd(&nz, 1);
  }
  __syncthreads();
  if (threadIdx.x == 0) *flag = (nz == 0) ? 1 : 0;
}

__device__ __forceinline__ int load_idx(const void* __restrict__ p, long long pos,
                                        int is64) {
  if (is64) return (int)(((const long long*)p)[pos]);
  return ((const int*)p)[pos];
}

__global__ void k_zero_i(int* __restrict__ p, int n) {
  int i = blockIdx.x * blockDim.x + threadIdx.x;
  if (i < n) p[i] = 0;
}

// ---------- chunk-total counts only (no per-node atomics) ----------
__global__ void k_count8(const void* __restrict__ ei, const int* __restrict__ flag,
                         int* __restrict__ ccnt, int E, float invNc) {
  __shared__ int bins[8];
  if (threadIdx.x < 8) bins[threadIdx.x] = 0;
  __syncthreads();
  int e = blockIdx.x * blockDim.x + threadIdx.x;
  if (e < E) {
    int is64 = *flag;
    int d = load_idx(ei, (long long)E + e, is64);
    int g = min(7, (int)((float)d * invNc));
    atomicAdd(&bins[g], 1);
  }
  __syncthreads();
  if (threadIdx.x < 8 && bins[threadIdx.x] > 0)
    atomicAdd(&ccnt[threadIdx.x], bins[threadIdx.x]);
}

// exclusive scan of 8 chunk counts -> chunk bases + fill tails
__global__ void k_cbase(const int* __restrict__ ccnt, int* __restrict__ cbase,
                        int* __restrict__ gtail) {
  if (threadIdx.x == 0) {
    int acc = 0;
    for (int g = 0; g < 8; ++g) {
      cbase[g] = acc;
      gtail[g] = acc;
      acc += ccnt[g];
    }
  }
}

// ---------- phase 1: bucket edges into chunk-grouped (d,s) pair arrays ----------
__global__ void k_bucket(const void* __restrict__ ei, const int* __restrict__ flag,
                         int* __restrict__ gtail, int* __restrict__ pair_d,
                         int* __restrict__ pair_s, int E, float invNc) {
  __shared__ int sd[BEB], ss[BEB];
  __shared__ int bins[8], bbase[8], cur[8];
  if (threadIdx.x < 8) bins[threadIdx.x] = 0;
  __syncthreads();
  int is64 = *flag;
  int base = blockIdx.x * BEB;
  int cnt = min(BEB, E - base);
  for (int i = threadIdx.x; i < cnt; i += TPB) {
    int e = base + i;
    int d = load_idx(ei, (long long)E + e, is64);
    int s = load_idx(ei, e, is64);
    sd[i] = d;
    ss[i] = s;
    int g = min(7, (int)((float)d * invNc));
    atomicAdd(&bins[g], 1);
  }
  __syncthreads();
  if (threadIdx.x < 8) {
    bbase[threadIdx.x] = atomicAdd(&gtail[threadIdx.x], bins[threadIdx.x]);
    cur[threadIdx.x] = 0;
  }
  __syncthreads();
  for (int i = threadIdx.x; i < cnt; i += TPB) {
    int d = sd[i];
    int s = ss[i];
    int g = min(7, (int)((float)d * invNc));
    int r = atomicAdd(&cur[g], 1);
    int pos = bbase[g] + r;
    __builtin_nontemporal_store(d, &pair_d[pos]);
    __builtin_nontemporal_store(s, &pair_s[pos]);
  }
}

// ---------- degree hist, XCD-pinned: chunk g's 100KB degi window stays in one L2 ----------
__global__ void k_hist_pinned(const int* __restrict__ cbase, const int* __restrict__ ccnt,
                              const int* __restrict__ pair_d, int* __restrict__ degi) {
  int g = blockIdx.x & 7;
  int seg = blockIdx.x >> 3;
  int cnt = ccnt[g];
  int base = seg * SEB;
  if (base >= cnt) return;
  int lim = min(base + SEB, cnt);
  const int* pd = pair_d + cbase[g];
  for (int i = base + threadIdx.x; i < lim; i += TPB) {
    int d = __builtin_nontemporal_load(&pd[i]);
    atomicAdd(&degi[d], 1);
  }
}

// inclusive block scan; emit per-block sums
__global__ void k_scan1(const int* __restrict__ degi, int* __restrict__ incl,
                        int* __restrict__ bsums, int n) {
  __shared__ int s[TPB];
  int i = blockIdx.x * TPB + threadIdx.x;
  int v = (i < n) ? degi[i] : 0;
  s[threadIdx.x] = v;
  __syncthreads();
#pragma unroll
  for (int off = 1; off < TPB; off <<= 1) {
    int t = (threadIdx.x >= off) ? s[threadIdx.x - off] : 0;
    __syncthreads();
    s[threadIdx.x] += t;
    __syncthreads();
  }
  if (i < n) incl[i] = s[threadIdx.x];
  if (threadIdx.x == TPB - 1) bsums[blockIdx.x] = s[TPB - 1];
}

// single-block exclusive scan of block sums (nb <= 1024)
__global__ void k_scan2(int* __restrict__ bsums, int nb) {
  __shared__ int s[1024];
  int t = threadIdx.x;
  int v = (t < nb) ? bsums[t] : 0;
  s[t] = v;
  __syncthreads();
#pragma unroll
  for (int off = 1; off < 1024; off <<= 1) {
    int u = (t >= off) ? s[t - off] : 0;
    __syncthreads();
    s[t] += u;
    __syncthreads();
  }
  if (t < nb) bsums[t] = s[t] - v;  // exclusive
}

// starts/cursor + dinv + packed meta {start, deg, dinv_bits, 0}
__global__ void k_finalize(const int* __restrict__ degi, const int* __restrict__ incl,
                           const int* __restrict__ bsums, int* __restrict__ cursor,
                           float* __restrict__ dinv, int4* __restrict__ meta, int n) {
  int i = blockIdx.x * TPB + threadIdx.x;
  if (i >= n) return;
  int dg = degi[i];
  int st = bsums[blockIdx.x] + incl[i] - dg;
  float di = rsqrtf((float)(dg + 1));  // +1 self-loop
  cursor[i] = st;
  dinv[i] = di;
  meta[i] = make_int4(st, dg, __float_as_int(di), 0);
}

// ---------- phase 2: CSR fill from chunk-grouped pairs (XCD-pinned) ----------
__global__ void k_scatter2(const int* __restrict__ cbase, const int* __restrict__ ccnt,
                           const int* __restrict__ pair_d, const int* __restrict__ pair_s,
                           int* __restrict__ cursor, int* __restrict__ ssrc) {
  int g = blockIdx.x & 7;
  int seg = blockIdx.x >> 3;
  int cnt = ccnt[g];
  int base = seg * SEB;
  if (base >= cnt) return;
  int lim = min(base + SEB, cnt);
  const int* pd = pair_d + cbase[g];
  const int* ps = pair_s + cbase[g];
  for (int i = base + threadIdx.x; i < lim; i += TPB) {
    int d = __builtin_nontemporal_load(&pd[i]);
    int s = __builtin_nontemporal_load(&ps[i]);
    int pos = atomicAdd(&cursor[d], 1);
    ssrc[pos] = s;
  }
}

// ---------- gx = x * dinv (16 channels) ----------
__global__ void k_prescale16(const float* __restrict__ x, const float* __restrict__ dinv,
                             float* __restrict__ gx, int n4) {
  int gid = blockIdx.x * blockDim.x + threadIdx.x;
  if (gid >= n4) return;
  int i = gid >> 2;
  float di = dinv[i];
  float4 v = reinterpret_cast<const float4*>(x)[gid];
  v.x *= di; v.y *= di; v.z *= di; v.w *= di;
  reinterpret_cast<float4*>(gx)[gid] = v;
}

// ---------- gather: 4 threads/dst; out = dinv[d]*(v[d] + sum_edges v[src]) ----------
template <int CH>  // 16: one float4/thread, 32: two float4/thread
__global__ void k_gatherT(const int4* __restrict__ meta, const int* __restrict__ ssrc,
                          const float* __restrict__ v, float* __restrict__ outp, int n) {
  int gid = blockIdx.x * blockDim.x + threadIdx.x;
  int dst = gid >> 2;
  int q = gid & 3;
  if (dst >= n) return;
  int4 md = meta[dst];
  int s0 = md.x;
  int dg = md.y;
  float dd = __int_as_float(md.z);
  size_t o0 = (size_t)q * 4;
  size_t o1 = o0 + 16;
  const float* rd = v + (size_t)dst * CH;
  float4 a0 = *reinterpret_cast<const float4*>(rd + o0);   // self term
  float4 a1;
  if (CH == 32) a1 = *reinterpret_cast<const float4*>(rd + o1);
  int j = 0;
  for (; j + 2 <= dg; j += 2) {
    int s1 = __builtin_nontemporal_load(&ssrc[s0 + j]);
    int s2 = __builtin_nontemporal_load(&ssrc[s0 + j + 1]);
    const float* r1 = v + (size_t)s1 * CH;
    const float* r2 = v + (size_t)s2 * CH;
    float4 v0 = *reinterpret_cast<const float4*>(r1 + o0);
    float4 w0 = *reinterpret_cast<const float4*>(r2 + o0);
    a0.x += v0.x + w0.x; a0.y += v0.y + w0.y; a0.z += v0.z + w0.z; a0.w += v0.w + w0.w;
    if (CH == 32) {
      float4 v1 = *reinterpret_cast<const float4*>(r1 + o1);
      float4 w1 = *reinterpret_cast<const float4*>(r2 + o1);
      a1.x += v1.x + w1.x; a1.y += v1.y + w1.y; a1.z += v1.z + w1.z; a1.w += v1.w + w1.w;
    }
  }
  if (j < dg) {
    int s1 = __builtin_nontemporal_load(&ssrc[s0 + j]);
    const float* r1 = v + (size_t)s1 * CH;
    float4 v0 = *reinterpret_cast<const float4*>(r1 + o0);
    a0.x += v0.x; a0.y += v0.y; a0.z += v0.z; a0.w += v0.w;
    if (CH == 32) {
      float4 v1 = *reinterpret_cast<const float4*>(r1 + o1);
      a1.x += v1.x; a1.y += v1.y; a1.z += v1.z; a1.w += v1.w;
    }
  }
  a0.x *= dd; a0.y *= dd; a0.z *= dd; a0.w *= dd;
  float* wr = outp + (size_t)dst * CH;
  *reinterpret_cast<float4*>(wr + o0) = a0;
  if (CH == 32) {
    a1.x *= dd; a1.y *= dd; a1.z *= dd; a1.w *= dd;
    *reinterpret_cast<float4*>(wr + o1) = a1;
  }
}

// ---------- transform: out = (h @ W + b) [relu] [* dinv] ----------
template <int IN, int OUT, bool RELU, bool PRESCALE>
__global__ void k_transform(const float* __restrict__ h, const float* __restrict__ W,
                            const float* __restrict__ b, const float* __restrict__ dinv,
                            float* __restrict__ outp, int n) {
  __shared__ float sW[IN * OUT];
  __shared__ float sB[OUT];
  for (int t = threadIdx.x; t < IN * OUT; t += blockDim.x) sW[t] = W[t];
  if (threadIdx.x < OUT) sB[threadIdx.x] = b[threadIdx.x];
  __syncthreads();
  int i = blockIdx.x * blockDim.x + threadIdx.x;
  if (i >= n) return;
  float xr[IN];
  const float4* hp = reinterpret_cast<const float4*>(h + (size_t)i * IN);
#pragma unroll
  for (int k4 = 0; k4 < IN / 4; ++k4) {
    float4 v = hp[k4];
    xr[k4 * 4 + 0] = v.x; xr[k4 * 4 + 1] = v.y;
    xr[k4 * 4 + 2] = v.z; xr[k4 * 4 + 3] = v.w;
  }
  float acc[OUT];
#pragma unroll
  for (int c = 0; c < OUT; ++c) acc[c] = sB[c];
#pragma unroll
  for (int k = 0; k < IN; ++k) {
    float xv = xr[k];
#pragma unroll
    for (int c = 0; c < OUT; ++c) acc[c] = fmaf(xv, sW[k * OUT + c], acc[c]);
  }
  float di = PRESCALE ? dinv[i] : 1.0f;
  float4* mp = reinterpret_cast<float4*>(outp + (size_t)i * OUT);
#pragma unroll
  for (int c4 = 0; c4 < OUT / 4; ++c4) {
    float4 o;
    o.x = acc[c4 * 4 + 0]; o.y = acc[c4 * 4 + 1];
    o.z = acc[c4 * 4 + 2]; o.w = acc[c4 * 4 + 3];
    if (RELU) {
      o.x = fmaxf(o.x, 0.0f); o.y = fmaxf(o.y, 0.0f);
      o.z = fmaxf(o.z, 0.0f); o.w = fmaxf(o.w, 0.0f);
    }
    if (PRESCALE) { o.x *= di; o.y *= di; o.z *= di; o.w *= di; }
    mp[c4] = o;
  }
}

extern "C" void kernel_launch(void* const* d_in, const int* in_sizes, int n_in,
                              void* d_out, int out_size, void* d_ws, size_t ws_size,
                              hipStream_t stream) {
  const float* x  = (const float*)d_in[0];
  const void*  ei = d_in[1];
  const float* W1 = (const float*)d_in[2];
  const float* b1 = (const float*)d_in[3];
  const float* W2 = (const float*)d_in[4];
  const float* b2 = (const float*)d_in[5];
  float* out = (float*)d_out;

  const int N = in_sizes[0] / 16;
  const int E = in_sizes[1] / 2;
  const int Nc = (N + 7) / 8;          // dst chunk size (locality heuristic only)
  const float invNc = 1.0f / (float)Nc;

  // workspace carve-up (256B aligned)
  char* p = (char*)d_ws;
  auto alloc = [&](size_t bytes) {
    char* r = p;
    p += (bytes + 255) & ~(size_t)255;
    return r;
  };
  int*   flag   = (int*)alloc(4);
  float* dinv   = (float*)alloc((size_t)N * 4);
  int*   degi   = (int*)alloc((size_t)N * 4);
  int*   incl   = (int*)alloc((size_t)N * 4);
  int*   cursor = (int*)alloc((size_t)N * 4);
  int4*  meta   = (int4*)alloc((size_t)N * 16);
  int*   bsums  = (int*)alloc(4096);
  int*   ccnt   = (int*)alloc(64);
  int*   cbase  = (int*)alloc(64);
  int*   gtail  = (int*)alloc(64);
  int*   ssrc   = (int*)alloc((size_t)E * 4);
  float* bufA   = (float*)alloc((size_t)N * 32 * 4);   // pair_d -> gx -> gh
  float* bufB   = (float*)alloc((size_t)N * 32 * 4);   // pair_s -> agg1 -> agg2
  // lifetimes: pairs die at k_scatter2/k_hist_pinned (before k_prescale16);
  // gx dies at k_gatherT<16>; agg1 dies at k_t1; gh dies at k_gatherT<32>.
  int*   pair_d = (int*)bufA;
  int*   pair_s = (int*)bufB;
  float* gx     = bufA;
  float* agg1   = bufB;
  float* gh     = bufA;
  float* agg2   = bufB;

  const int gN  = (N + TPB - 1) / TPB;
  const int gE  = (E + TPB - 1) / TPB;
  const int gN4 = (N * 4 + TPB - 1) / TPB;
  const int gBk = (E + BEB - 1) / BEB;
  const int gS2 = ((E + SEB - 1) / SEB) * 8;

  // 0. index-width detect + zero chunk counts
  k_detect_i64<<<1, TPB, 0, stream>>>((const unsigned int*)ei, E, flag, ccnt);
  // 1. chunk totals (streaming, no per-node atomics) + chunk bases
  k_count8<<<gE, TPB, 0, stream>>>(ei, flag, ccnt, E, invNc);
  k_cbase<<<1, 64, 0, stream>>>(ccnt, cbase, gtail);
  k_zero_i<<<gN, TPB, 0, stream>>>(degi, N);
  // 2. bucket edges by chunk; XCD-pinned degree hist
  k_bucket<<<gBk, TPB, 0, stream>>>(ei, flag, gtail, pair_d, pair_s, E, invNc);
  k_hist_pinned<<<gS2, TPB, 0, stream>>>(cbase, ccnt, pair_d, degi);
  // 3. scans -> starts/cursor/dinv/meta; XCD-pinned CSR fill
  k_scan1<<<gN, TPB, 0, stream>>>(degi, incl, bsums, N);
  k_scan2<<<1, 1024, 0, stream>>>(bsums, gN);
  k_finalize<<<gN, TPB, 0, stream>>>(degi, incl, bsums, cursor, dinv, meta, N);
  k_scatter2<<<gS2, TPB, 0, stream>>>(cbase, ccnt, pair_d, pair_s, cursor, ssrc);
  // 4. layer 1: aggregate in 16-dim input space, then transform
  k_prescale16<<<gN4, TPB, 0, stream>>>(x, dinv, gx, N * 4);
  k_gatherT<16><<<gN4, TPB, 0, stream>>>(meta, ssrc, gx, agg1, N);
  k_transform<16, 32, true, true><<<gN, TPB, 0, stream>>>(agg1, W1, b1, dinv, gh, N);
  // 5. layer 2: aggregate 32-dim, then transform -> out
  k_gatherT<32><<<gN4, TPB, 0, stream>>>(meta, ssrc, gh, agg2, N);
  k_transform<32, 32, false, false><<<gN, TPB, 0, stream>>>(agg2, W2, b2, dinv, out, N);
}

// Round 8
// 490.556 us; speedup vs baseline: 1.1909x; 1.1909x over previous
//
#include <hip/hip_runtime.h>

#define TPB 256
#define BEB 2048  // edges per bucket block (LDS-staged)
#define SEB 2048  // edges per scatter2/hist block

// ---------- index-width detect + zero cum counters ----------
__global__ void k_detect_i64(const unsigned int* __restrict__ ei, int E,
                             int* __restrict__ flag, int* __restrict__ cum) {
  __shared__ int nz;
  if (threadIdx.x == 0) nz = 0;
  if (threadIdx.x < 7) cum[threadIdx.x] = 0;
  __syncthreads();
  int step = E / 4096;
  if (step < 1) step = 1;
  for (int t = threadIdx.x; t < 4096; t += blockDim.x) {
    long long pos = 1 + 2LL * (long long)t * step;   // odd dword positions
    if (pos < 2LL * (long long)E && ei[pos] != 0u) atomicAdd(&nz, 1);
  }
  __syncthreads();
  if (threadIdx.x == 0) *flag = (nz == 0) ? 1 : 0;
}

__device__ __forceinline__ int load_idx(const void* __restrict__ p, long long pos,
                                        int is64) {
  if (is64) return (int)(((const long long*)p)[pos]);
  return ((const int*)p)[pos];
}

__global__ void k_zero_i(int* __restrict__ p, int n) {
  int i = blockIdx.x * blockDim.x + threadIdx.x;
  if (i < n) p[i] = 0;
}

// ---------- cumulative chunk counts: cum[k] = #(d < (k+1)*Nc), k=0..6 ----------
// Branchless predicate counters in registers; NO per-edge LDS/global atomics.
__global__ void k_count8(const void* __restrict__ ei, const int* __restrict__ flag,
                         int* __restrict__ cum, int E, int Nc) {
  int is64 = *flag;
  int c[7] = {0, 0, 0, 0, 0, 0, 0};
  int stride = gridDim.x * blockDim.x;
  for (int e = blockIdx.x * blockDim.x + threadIdx.x; e < E; e += stride) {
    int d = load_idx(ei, (long long)E + e, is64);
#pragma unroll
    for (int k = 0; k < 7; ++k) c[k] += (d < (k + 1) * Nc) ? 1 : 0;
  }
#pragma unroll
  for (int k = 0; k < 7; ++k)
#pragma unroll
    for (int off = 32; off >= 1; off >>= 1) c[k] += __shfl_xor(c[k], off);
  __shared__ int red[4][7];
  int lane = threadIdx.x & 63, wid = threadIdx.x >> 6;
  if (lane == 0) {
#pragma unroll
    for (int k = 0; k < 7; ++k) red[wid][k] = c[k];
  }
  __syncthreads();
  if (threadIdx.x < 7) {
    int s = red[0][threadIdx.x] + red[1][threadIdx.x] +
            red[2][threadIdx.x] + red[3][threadIdx.x];
    if (s) atomicAdd(&cum[threadIdx.x], s);
  }
}

// cum -> per-chunk counts, bases, fill tails
__global__ void k_cbase(const int* __restrict__ cum, int* __restrict__ ccnt,
                        int* __restrict__ cbase, int* __restrict__ gtail, int E) {
  if (threadIdx.x == 0) {
    int prev = 0, acc = 0;
    for (int g = 0; g < 8; ++g) {
      int cg = ((g < 7) ? cum[g] : E) - prev;
      prev = (g < 7) ? cum[g] : E;
      ccnt[g] = cg;
      cbase[g] = acc;
      gtail[g] = acc;
      acc += cg;
    }
  }
}

// ---------- bucket edges into chunk-grouped packed (d,s) pairs ----------
// Pass A: stage in LDS + predicate-count bins (no LDS atomics).
// Pass B: ballot-aggregated placement (8 conflict-free LDS atomics per wave-trip).
__global__ void k_bucket(const void* __restrict__ ei, const int* __restrict__ flag,
                         int* __restrict__ gtail, unsigned long long* __restrict__ pair,
                         int E, int Nc) {
  __shared__ int sd[BEB], ss[BEB];
  __shared__ int bbase[8], cur[8];
  __shared__ int red[4][7];
  int is64 = *flag;
  int base = blockIdx.x * BEB;
  int cnt = min(BEB, E - base);
  int c[7] = {0, 0, 0, 0, 0, 0, 0};
  for (int i = threadIdx.x; i < cnt; i += TPB) {
    int e = base + i;
    int d = load_idx(ei, (long long)E + e, is64);
    int s = load_idx(ei, e, is64);
    sd[i] = d;
    ss[i] = s;
#pragma unroll
    for (int k = 0; k < 7; ++k) c[k] += (d < (k + 1) * Nc) ? 1 : 0;
  }
#pragma unroll
  for (int k = 0; k < 7; ++k)
#pragma unroll
    for (int off = 32; off >= 1; off >>= 1) c[k] += __shfl_xor(c[k], off);
  int lane = threadIdx.x & 63, wid = threadIdx.x >> 6;
  if (lane == 0) {
#pragma unroll
    for (int k = 0; k < 7; ++k) red[wid][k] = c[k];
  }
  __syncthreads();
  if (threadIdx.x < 8) {
    int g = threadIdx.x;
    int hi = (g < 7) ? (red[0][g] + red[1][g] + red[2][g] + red[3][g]) : cnt;
    int lo = (g > 0) ? (red[0][g - 1] + red[1][g - 1] + red[2][g - 1] + red[3][g - 1]) : 0;
    bbase[g] = atomicAdd(&gtail[g], hi - lo);
    cur[g] = 0;
  }
  __syncthreads();
  int trips = (cnt + TPB - 1) / TPB;
  unsigned long long lt = (1ULL << lane) - 1ULL;
  for (int t = 0; t < trips; ++t) {
    int i = t * TPB + threadIdx.x;
    bool act = i < cnt;
    int d = act ? sd[i] : 0;
    int s = act ? ss[i] : 0;
    int g = 0;
#pragma unroll
    for (int k = 1; k <= 7; ++k) g += (d >= k * Nc) ? 1 : 0;
    unsigned long long m0 = __ballot(act && g == 0);
    unsigned long long m1 = __ballot(act && g == 1);
    unsigned long long m2 = __ballot(act && g == 2);
    unsigned long long m3 = __ballot(act && g == 3);
    unsigned long long m4 = __ballot(act && g == 4);
    unsigned long long m5 = __ballot(act && g == 5);
    unsigned long long m6 = __ballot(act && g == 6);
    unsigned long long m7 = __ballot(act && g == 7);
    int wb = 0;
    if (lane < 8) {
      unsigned long long mm =
          lane < 4 ? (lane < 2 ? (lane == 0 ? m0 : m1) : (lane == 2 ? m2 : m3))
                   : (lane < 6 ? (lane == 4 ? m4 : m5) : (lane == 6 ? m6 : m7));
      wb = atomicAdd(&cur[lane], (int)__popcll(mm));
    }
    int mybase = __shfl(wb, g);
    unsigned long long mk =
        g < 4 ? (g < 2 ? (g == 0 ? m0 : m1) : (g == 2 ? m2 : m3))
              : (g < 6 ? (g == 4 ? m4 : m5) : (g == 6 ? m6 : m7));
    int rank = (int)__popcll(mk & lt);
    if (act) {
      int pos = bbase[g] + mybase + rank;
      unsigned long long pk =
          ((unsigned long long)(unsigned)s << 32) | (unsigned)d;
      __builtin_nontemporal_store(pk, &pair[pos]);
    }
  }
}

// ---------- degree hist, XCD-pinned: chunk g's 100KB degi window in one L2 ----------
__global__ void k_hist_pinned(const int* __restrict__ cbase, const int* __restrict__ ccnt,
                              const int2* __restrict__ pair, int* __restrict__ degi) {
  int g = blockIdx.x & 7;
  int seg = blockIdx.x >> 3;
  int cnt = ccnt[g];
  int base = seg * SEB;
  if (base >= cnt) return;
  int lim = min(base + SEB, cnt);
  const int2* pp = pair + cbase[g];
  for (int i = base + threadIdx.x; i < lim; i += TPB) {
    int2 pr = pp[i];
    atomicAdd(&degi[pr.x], 1);
  }
}

// inclusive block scan; emit per-block sums
__global__ void k_scan1(const int* __restrict__ degi, int* __restrict__ incl,
                        int* __restrict__ bsums, int n) {
  __shared__ int s[TPB];
  int i = blockIdx.x * TPB + threadIdx.x;
  int v = (i < n) ? degi[i] : 0;
  s[threadIdx.x] = v;
  __syncthreads();
#pragma unroll
  for (int off = 1; off < TPB; off <<= 1) {
    int t = (threadIdx.x >= off) ? s[threadIdx.x - off] : 0;
    __syncthreads();
    s[threadIdx.x] += t;
    __syncthreads();
  }
  if (i < n) incl[i] = s[threadIdx.x];
  if (threadIdx.x == TPB - 1) bsums[blockIdx.x] = s[TPB - 1];
}

// single-block exclusive scan of block sums (nb <= 1024)
__global__ void k_scan2(int* __restrict__ bsums, int nb) {
  __shared__ int s[1024];
  int t = threadIdx.x;
  int v = (t < nb) ? bsums[t] : 0;
  s[t] = v;
  __syncthreads();
#pragma unroll
  for (int off = 1; off < 1024; off <<= 1) {
    int u = (t >= off) ? s[t - off] : 0;
    __syncthreads();
    s[t] += u;
    __syncthreads();
  }
  if (t < nb) bsums[t] = s[t] - v;  // exclusive
}

// starts/cursor + dinv + packed meta {start, deg, dinv_bits, 0}
__global__ void k_finalize(const int* __restrict__ degi, const int* __restrict__ incl,
                           const int* __restrict__ bsums, int* __restrict__ cursor,
                           float* __restrict__ dinv, int4* __restrict__ meta, int n) {
  int i = blockIdx.x * TPB + threadIdx.x;
  if (i >= n) return;
  int dg = degi[i];
  int st = bsums[blockIdx.x] + incl[i] - dg;
  float di = rsqrtf((float)(dg + 1));  // +1 self-loop
  cursor[i] = st;
  dinv[i] = di;
  meta[i] = make_int4(st, dg, __float_as_int(di), 0);
}

// ---------- CSR fill from chunk-grouped pairs (XCD-pinned) ----------
__global__ void k_scatter2(const int* __restrict__ cbase, const int* __restrict__ ccnt,
                           const int2* __restrict__ pair, int* __restrict__ cursor,
                           int* __restrict__ ssrc) {
  int g = blockIdx.x & 7;
  int seg = blockIdx.x >> 3;
  int cnt = ccnt[g];
  int base = seg * SEB;
  if (base >= cnt) return;
  int lim = min(base + SEB, cnt);
  const int2* pp = pair + cbase[g];
  for (int i = base + threadIdx.x; i < lim; i += TPB) {
    int2 pr = pp[i];
    int pos = atomicAdd(&cursor[pr.x], 1);
    ssrc[pos] = pr.y;
  }
}

// ---------- gx = x * dinv (16 channels) ----------
__global__ void k_prescale16(const float* __restrict__ x, const float* __restrict__ dinv,
                             float* __restrict__ gx, int n4) {
  int gid = blockIdx.x * blockDim.x + threadIdx.x;
  if (gid >= n4) return;
  int i = gid >> 2;
  float di = dinv[i];
  float4 v = reinterpret_cast<const float4*>(x)[gid];
  v.x *= di; v.y *= di; v.z *= di; v.w *= di;
  reinterpret_cast<float4*>(gx)[gid] = v;
}

// ---------- gather: 4 threads/dst; out = dinv[d]*(v[d] + sum_edges v[src]) ----------
template <int CH>  // 16: one float4/thread, 32: two float4/thread
__global__ void k_gatherT(const int4* __restrict__ meta, const int* __restrict__ ssrc,
                          const float* __restrict__ v, float* __restrict__ outp, int n) {
  int gid = blockIdx.x * blockDim.x + threadIdx.x;
  int dst = gid >> 2;
  int q = gid & 3;
  if (dst >= n) return;
  int4 md = meta[dst];
  int s0 = md.x;
  int dg = md.y;
  float dd = __int_as_float(md.z);
  size_t o0 = (size_t)q * 4;
  size_t o1 = o0 + 16;
  const float* rd = v + (size_t)dst * CH;
  float4 a0 = *reinterpret_cast<const float4*>(rd + o0);   // self term
  float4 a1;
  if (CH == 32) a1 = *reinterpret_cast<const float4*>(rd + o1);
  int j = 0;
  for (; j + 2 <= dg; j += 2) {
    int s1 = __builtin_nontemporal_load(&ssrc[s0 + j]);
    int s2 = __builtin_nontemporal_load(&ssrc[s0 + j + 1]);
    const float* r1 = v + (size_t)s1 * CH;
    const float* r2 = v + (size_t)s2 * CH;
    float4 v0 = *reinterpret_cast<const float4*>(r1 + o0);
    float4 w0 = *reinterpret_cast<const float4*>(r2 + o0);
    a0.x += v0.x + w0.x; a0.y += v0.y + w0.y; a0.z += v0.z + w0.z; a0.w += v0.w + w0.w;
    if (CH == 32) {
      float4 v1 = *reinterpret_cast<const float4*>(r1 + o1);
      float4 w1 = *reinterpret_cast<const float4*>(r2 + o1);
      a1.x += v1.x + w1.x; a1.y += v1.y + w1.y; a1.z += v1.z + w1.z; a1.w += v1.w + w1.w;
    }
  }
  if (j < dg) {
    int s1 = __builtin_nontemporal_load(&ssrc[s0 + j]);
    const float* r1 = v + (size_t)s1 * CH;
    float4 v0 = *reinterpret_cast<const float4*>(r1 + o0);
    a0.x += v0.x; a0.y += v0.y; a0.z += v0.z; a0.w += v0.w;
    if (CH == 32) {
      float4 v1 = *reinterpret_cast<const float4*>(r1 + o1);
      a1.x += v1.x; a1.y += v1.y; a1.z += v1.z; a1.w += v1.w;
    }
  }
  a0.x *= dd; a0.y *= dd; a0.z *= dd; a0.w *= dd;
  float* wr = outp + (size_t)dst * CH;
  *reinterpret_cast<float4*>(wr + o0) = a0;
  if (CH == 32) {
    a1.x *= dd; a1.y *= dd; a1.z *= dd; a1.w *= dd;
    *reinterpret_cast<float4*>(wr + o1) = a1;
  }
}

// ---------- transform: out = (h @ W + b) [relu] [* dinv] ----------
template <int IN, int OUT, bool RELU, bool PRESCALE>
__global__ void k_transform(const float* __restrict__ h, const float* __restrict__ W,
                            const float* __restrict__ b, const float* __restrict__ dinv,
                            float* __restrict__ outp, int n) {
  __shared__ float sW[IN * OUT];
  __shared__ float sB[OUT];
  for (int t = threadIdx.x; t < IN * OUT; t += blockDim.x) sW[t] = W[t];
  if (threadIdx.x < OUT) sB[threadIdx.x] = b[threadIdx.x];
  __syncthreads();
  int i = blockIdx.x * blockDim.x + threadIdx.x;
  if (i >= n) return;
  float xr[IN];
  const float4* hp = reinterpret_cast<const float4*>(h + (size_t)i * IN);
#pragma unroll
  for (int k4 = 0; k4 < IN / 4; ++k4) {
    float4 v = hp[k4];
    xr[k4 * 4 + 0] = v.x; xr[k4 * 4 + 1] = v.y;
    xr[k4 * 4 + 2] = v.z; xr[k4 * 4 + 3] = v.w;
  }
  float acc[OUT];
#pragma unroll
  for (int c = 0; c < OUT; ++c) acc[c] = sB[c];
#pragma unroll
  for (int k = 0; k < IN; ++k) {
    float xv = xr[k];
#pragma unroll
    for (int c = 0; c < OUT; ++c) acc[c] = fmaf(xv, sW[k * OUT + c], acc[c]);
  }
  float di = PRESCALE ? dinv[i] : 1.0f;
  float4* mp = reinterpret_cast<float4*>(outp + (size_t)i * OUT);
#pragma unroll
  for (int c4 = 0; c4 < OUT / 4; ++c4) {
    float4 o;
    o.x = acc[c4 * 4 + 0]; o.y = acc[c4 * 4 + 1];
    o.z = acc[c4 * 4 + 2]; o.w = acc[c4 * 4 + 3];
    if (RELU) {
      o.x = fmaxf(o.x, 0.0f); o.y = fmaxf(o.y, 0.0f);
      o.z = fmaxf(o.z, 0.0f); o.w = fmaxf(o.w, 0.0f);
    }
    if (PRESCALE) { o.x *= di; o.y *= di; o.z *= di; o.w *= di; }
    mp[c4] = o;
  }
}

extern "C" void kernel_launch(void* const* d_in, const int* in_sizes, int n_in,
                              void* d_out, int out_size, void* d_ws, size_t ws_size,
                              hipStream_t stream) {
  const float* x  = (const float*)d_in[0];
  const void*  ei = d_in[1];
  const float* W1 = (const float*)d_in[2];
  const float* b1 = (const float*)d_in[3];
  const float* W2 = (const float*)d_in[4];
  const float* b2 = (const float*)d_in[5];
  float* out = (float*)d_out;

  const int N = in_sizes[0] / 16;
  const int E = in_sizes[1] / 2;
  const int Nc = (N + 7) / 8;          // dst chunk size (locality heuristic only)

  // workspace carve-up (256B aligned)
  char* p = (char*)d_ws;
  auto alloc = [&](size_t bytes) {
    char* r = p;
    p += (bytes + 255) & ~(size_t)255;
    return r;
  };
  int*   flag   = (int*)alloc(4);
  float* dinv   = (float*)alloc((size_t)N * 4);
  int*   degi   = (int*)alloc((size_t)N * 4);
  int*   incl   = (int*)alloc((size_t)N * 4);
  int*   cursor = (int*)alloc((size_t)N * 4);
  int4*  meta   = (int4*)alloc((size_t)N * 16);
  int*   bsums  = (int*)alloc(4096);
  int*   cum    = (int*)alloc(64);
  int*   ccnt   = (int*)alloc(64);
  int*   cbase  = (int*)alloc(64);
  int*   gtail  = (int*)alloc(64);
  int*   ssrc   = (int*)alloc((size_t)E * 4);
  float* bufA   = (float*)alloc((size_t)N * 32 * 4);   // pair(int2,19.2MB) -> gx -> gh
  float* bufB   = (float*)alloc((size_t)N * 32 * 4);   // agg1 -> agg2
  // lifetimes: pair dies at k_scatter2 (before k_prescale16 writes gx);
  // gx dies at gatherT<16>; agg1 dies at transform1; gh dies at gatherT<32>.
  unsigned long long* pairW = (unsigned long long*)bufA;
  const int2*         pairR = (const int2*)bufA;
  float* gx   = bufA;
  float* agg1 = bufB;
  float* gh   = bufA;
  float* agg2 = bufB;

  const int gN  = (N + TPB - 1) / TPB;
  const int gN4 = (N * 4 + TPB - 1) / TPB;
  const int gBk = (E + BEB - 1) / BEB;
  const int gS2 = ((E + SEB - 1) / SEB) * 8;

  // 0. index-width detect + zero cum
  k_detect_i64<<<1, TPB, 0, stream>>>((const unsigned int*)ei, E, flag, cum);
  // 1. chunk cumulative counts (register predicates) -> bases
  k_count8<<<512, TPB, 0, stream>>>(ei, flag, cum, E, Nc);
  k_cbase<<<1, 64, 0, stream>>>(cum, ccnt, cbase, gtail, E);
  k_zero_i<<<gN, TPB, 0, stream>>>(degi, N);
  // 2. bucket edges by chunk (ballot-aggregated); XCD-pinned degree hist
  k_bucket<<<gBk, TPB, 0, stream>>>(ei, flag, gtail, pairW, E, Nc);
  k_hist_pinned<<<gS2, TPB, 0, stream>>>(cbase, ccnt, pairR, degi);
  // 3. scans -> starts/cursor/dinv/meta; XCD-pinned CSR fill
  k_scan1<<<gN, TPB, 0, stream>>>(degi, incl, bsums, N);
  k_scan2<<<1, 1024, 0, stream>>>(bsums, gN);
  k_finalize<<<gN, TPB, 0, stream>>>(degi, incl, bsums, cursor, dinv, meta, N);
  k_scatter2<<<gS2, TPB, 0, stream>>>(cbase, ccnt, pairR, cursor, ssrc);
  // 4. layer 1: aggregate in 16-dim input space, then transform
  k_prescale16<<<gN4, TPB, 0, stream>>>(x, dinv, gx, N * 4);
  k_gatherT<16><<<gN4, TPB, 0, stream>>>(meta, ssrc, gx, agg1, N);
  k_transform<16, 32, true, true><<<gN, TPB, 0, stream>>>(agg1, W1, b1, dinv, gh, N);
  // 5. layer 2: aggregate 32-dim, then transform -> out
  k_gatherT<32><<<gN4, TPB, 0, stream>>>(meta, ssrc, gh, agg2, N);
  k_transform<32, 32, false, false><<<gN, TPB, 0, stream>>>(agg2, W2, b2, dinv, out, N);
}

// Round 9
// 339.764 us; speedup vs baseline: 1.7194x; 1.4438x over previous
//
#include <hip/hip_runtime.h>

#define TPB 256
#define BEB 2048   // edges per level-1 bucket block
#define SEB 2048   // edges per scnt slab
#define PEB 8192   // edges per place2 slab
#define NS_SH 7    // 128 nodes per sub-bucket
#define NS (1 << NS_SH)
#define CAP3 4096  // sort3 LDS capacity (mean 1531, +65 sigma)

// ---------- index-width detect + zero cum counters ----------
__global__ void k_detect_i64(const unsigned int* __restrict__ ei, int E,
                             int* __restrict__ flag, int* __restrict__ cum) {
  __shared__ int nz;
  if (threadIdx.x == 0) nz = 0;
  if (threadIdx.x < 7) cum[threadIdx.x] = 0;
  __syncthreads();
  int step = E / 4096;
  if (step < 1) step = 1;
  for (int t = threadIdx.x; t < 4096; t += blockDim.x) {
    long long pos = 1 + 2LL * (long long)t * step;   // odd dword positions
    if (pos < 2LL * (long long)E && ei[pos] != 0u) atomicAdd(&nz, 1);
  }
  __syncthreads();
  if (threadIdx.x == 0) *flag = (nz == 0) ? 1 : 0;
}

__device__ __forceinline__ int load_idx(const void* __restrict__ p, long long pos,
                                        int is64) {
  if (is64) return (int)(((const long long*)p)[pos]);
  return ((const int*)p)[pos];
}

__global__ void k_zero_i(int* __restrict__ p, int n) {
  int i = blockIdx.x * blockDim.x + threadIdx.x;
  if (i < n) p[i] = 0;
}

// ---------- cumulative chunk counts: cum[k] = #(d < (k+1)*Nc) ----------
__global__ void k_count8(const void* __restrict__ ei, const int* __restrict__ flag,
                         int* __restrict__ cum, int E, int Nc) {
  int is64 = *flag;
  int c[7] = {0, 0, 0, 0, 0, 0, 0};
  int stride = gridDim.x * blockDim.x;
  for (int e = blockIdx.x * blockDim.x + threadIdx.x; e < E; e += stride) {
    int d = load_idx(ei, (long long)E + e, is64);
#pragma unroll
    for (int k = 0; k < 7; ++k) c[k] += (d < (k + 1) * Nc) ? 1 : 0;
  }
#pragma unroll
  for (int k = 0; k < 7; ++k)
#pragma unroll
    for (int off = 32; off >= 1; off >>= 1) c[k] += __shfl_xor(c[k], off);
  __shared__ int red[4][7];
  int lane = threadIdx.x & 63, wid = threadIdx.x >> 6;
  if (lane == 0) {
#pragma unroll
    for (int k = 0; k < 7; ++k) red[wid][k] = c[k];
  }
  __syncthreads();
  if (threadIdx.x < 7) {
    int s = red[0][threadIdx.x] + red[1][threadIdx.x] +
            red[2][threadIdx.x] + red[3][threadIdx.x];
    if (s) atomicAdd(&cum[threadIdx.x], s);
  }
}

// cum -> per-chunk counts, bases, fill tails
__global__ void k_cbase(const int* __restrict__ cum, int* __restrict__ ccnt,
                        int* __restrict__ cbase, int* __restrict__ gtail, int E) {
  if (threadIdx.x == 0) {
    int prev = 0, acc = 0;
    for (int g = 0; g < 8; ++g) {
      int cg = ((g < 7) ? cum[g] : E) - prev;
      prev = (g < 7) ? cum[g] : E;
      ccnt[g] = cg;
      cbase[g] = acc;
      gtail[g] = acc;
      acc += cg;
    }
  }
}

// ---------- level-1 bucket: chunk-grouped packed (d,s) pairs ----------
__global__ void k_bucket(const void* __restrict__ ei, const int* __restrict__ flag,
                         int* __restrict__ gtail, unsigned long long* __restrict__ pair,
                         int E, int Nc) {
  __shared__ int sd[BEB], ss[BEB];
  __shared__ int bbase[8], cur[8];
  __shared__ int red[4][7];
  int is64 = *flag;
  int base = blockIdx.x * BEB;
  int cnt = min(BEB, E - base);
  int c[7] = {0, 0, 0, 0, 0, 0, 0};
  for (int i = threadIdx.x; i < cnt; i += TPB) {
    int e = base + i;
    int d = load_idx(ei, (long long)E + e, is64);
    int s = load_idx(ei, e, is64);
    sd[i] = d;
    ss[i] = s;
#pragma unroll
    for (int k = 0; k < 7; ++k) c[k] += (d < (k + 1) * Nc) ? 1 : 0;
  }
#pragma unroll
  for (int k = 0; k < 7; ++k)
#pragma unroll
    for (int off = 32; off >= 1; off >>= 1) c[k] += __shfl_xor(c[k], off);
  int lane = threadIdx.x & 63, wid = threadIdx.x >> 6;
  if (lane == 0) {
#pragma unroll
    for (int k = 0; k < 7; ++k) red[wid][k] = c[k];
  }
  __syncthreads();
  if (threadIdx.x < 8) {
    int g = threadIdx.x;
    int hi = (g < 7) ? (red[0][g] + red[1][g] + red[2][g] + red[3][g]) : cnt;
    int lo = (g > 0) ? (red[0][g - 1] + red[1][g - 1] + red[2][g - 1] + red[3][g - 1]) : 0;
    bbase[g] = atomicAdd(&gtail[g], hi - lo);
    cur[g] = 0;
  }
  __syncthreads();
  int trips = (cnt + TPB - 1) / TPB;
  unsigned long long lt = (1ULL << lane) - 1ULL;
  for (int t = 0; t < trips; ++t) {
    int i = t * TPB + threadIdx.x;
    bool act = i < cnt;
    int d = act ? sd[i] : 0;
    int s = act ? ss[i] : 0;
    int g = 0;
#pragma unroll
    for (int k = 1; k <= 7; ++k) g += (d >= k * Nc) ? 1 : 0;
    unsigned long long m0 = __ballot(act && g == 0);
    unsigned long long m1 = __ballot(act && g == 1);
    unsigned long long m2 = __ballot(act && g == 2);
    unsigned long long m3 = __ballot(act && g == 3);
    unsigned long long m4 = __ballot(act && g == 4);
    unsigned long long m5 = __ballot(act && g == 5);
    unsigned long long m6 = __ballot(act && g == 6);
    unsigned long long m7 = __ballot(act && g == 7);
    int wb = 0;
    if (lane < 8) {
      unsigned long long mm =
          lane < 4 ? (lane < 2 ? (lane == 0 ? m0 : m1) : (lane == 2 ? m2 : m3))
                   : (lane < 6 ? (lane == 4 ? m4 : m5) : (lane == 6 ? m6 : m7));
      wb = atomicAdd(&cur[lane], (int)__popcll(mm));
    }
    int mybase = __shfl(wb, g);
    unsigned long long mk =
        g < 4 ? (g < 2 ? (g == 0 ? m0 : m1) : (g == 2 ? m2 : m3))
              : (g < 6 ? (g == 4 ? m4 : m5) : (g == 6 ? m6 : m7));
    int rank = (int)__popcll(mk & lt);
    if (act) {
      int pos = bbase[g] + mybase + rank;
      unsigned long long pk =
          ((unsigned long long)(unsigned)s << 32) | (unsigned)d;
      __builtin_nontemporal_store(pk, &pair[pos]);
    }
  }
}

// ---------- sub-bucket counts (LDS hist over 196 addrs; coalesced merge) ----------
__global__ void k_scnt(const int* __restrict__ cbase, const int* __restrict__ ccnt,
                       const int2* __restrict__ pair, int* __restrict__ scnt,
                       int nsb_c, int Nc) {
  __shared__ int hist[256];
  for (int t = threadIdx.x; t < nsb_c; t += TPB) hist[t] = 0;
  __syncthreads();
  int g = blockIdx.x & 7, seg = blockIdx.x >> 3;
  int cnt = ccnt[g];
  int base = seg * SEB;
  if (base < cnt) {
    int lim = min(base + SEB, cnt);
    const int2* pp = pair + cbase[g];
    int lo = g * Nc;
    for (int i = base + threadIdx.x; i < lim; i += TPB)
      atomicAdd(&hist[(pp[i].x - lo) >> NS_SH], 1);
  }
  __syncthreads();
  for (int t = threadIdx.x; t < nsb_c; t += TPB)
    if (hist[t]) atomicAdd(&scnt[g * nsb_c + t], hist[t]);
}

// ---------- exclusive scan of nsb (<=2048) sub-bucket counts ----------
__global__ void k_sbase(const int* __restrict__ scnt, int* __restrict__ sbase,
                        int* __restrict__ stail, int nsb) {
  __shared__ int p[1024];
  int t = threadIdx.x;  // 1024 threads
  int i0 = 2 * t, i1 = 2 * t + 1;
  int v0 = (i0 < nsb) ? scnt[i0] : 0;
  int v1 = (i1 < nsb) ? scnt[i1] : 0;
  p[t] = v0 + v1;
  __syncthreads();
#pragma unroll
  for (int off = 1; off < 1024; off <<= 1) {
    int u = (t >= off) ? p[t - off] : 0;
    __syncthreads();
    p[t] += u;
    __syncthreads();
  }
  int excl = p[t] - (v0 + v1);
  if (i0 < nsb) { sbase[i0] = excl; stail[i0] = excl; }
  if (i1 < nsb) { sbase[i1] = excl + v0; stail[i1] = excl + v0; }
}

// ---------- place2: LDS counting-sort slab by sub-bucket, emit coalesced runs ----------
__global__ void k_place2(const int* __restrict__ cbase, const int* __restrict__ ccnt,
                         const unsigned long long* __restrict__ pair,
                         int* __restrict__ stail, unsigned long long* __restrict__ pair2,
                         int nsb_c, int Nc) {
  __shared__ unsigned long long sorted[PEB];
  __shared__ int hist[256], bb[256], gb[256], cur[256];
  int g = blockIdx.x & 7, seg = blockIdx.x >> 3;
  int cnt = ccnt[g];
  int base = seg * PEB;
  if (base >= cnt) return;  // block-uniform
  int lim = min(base + PEB, cnt);
  int lo = g * Nc;
  const unsigned long long* pp = pair + cbase[g];
  for (int t = threadIdx.x; t < 256; t += TPB) hist[t] = 0;
  __syncthreads();
  // pass 1: count
  for (int i = base + threadIdx.x; i < lim; i += TPB) {
    int d = (int)(unsigned)(pp[i] & 0xffffffffULL);
    atomicAdd(&hist[(d - lo) >> NS_SH], 1);
  }
  __syncthreads();
  // exclusive scan hist -> bb
  {
    int t = threadIdx.x;
    int v = hist[t];
    bb[t] = v;
    __syncthreads();
#pragma unroll
    for (int off = 1; off < 256; off <<= 1) {
      int u = (t >= off) ? bb[t - off] : 0;
      __syncthreads();
      bb[t] += u;
      __syncthreads();
    }
    bb[t] -= v;
  }
  // reserve global space per sub-bucket
  for (int t = threadIdx.x; t < nsb_c; t += TPB) {
    gb[t] = hist[t] ? atomicAdd(&stail[g * nsb_c + t], hist[t]) : 0;
    cur[t] = 0;
  }
  __syncthreads();
  // pass 2: sort into LDS
  for (int i = base + threadIdx.x; i < lim; i += TPB) {
    unsigned long long pk = pp[i];
    int d = (int)(unsigned)(pk & 0xffffffffULL);
    int sb = (d - lo) >> NS_SH;
    int r = atomicAdd(&cur[sb], 1);
    sorted[bb[sb] + r] = pk;
  }
  __syncthreads();
  // emit: linear over sorted -> contiguous runs per sub-bucket
  int n = lim - base;
  for (int i = threadIdx.x; i < n; i += TPB) {
    unsigned long long pk = sorted[i];
    int d = (int)(unsigned)(pk & 0xffffffffULL);
    int sb = (d - lo) >> NS_SH;
    pair2[gb[sb] + (i - bb[sb])] = pk;
  }
}

// ---------- degi from sub-bucket-grouped pairs (coalesced writes) ----------
__global__ void k_hist3(const int* __restrict__ scnt, const int* __restrict__ sbase,
                        const int2* __restrict__ pair2, int* __restrict__ degi,
                        int nsb_c, int Nc, int N) {
  __shared__ int hist[NS];
  int sb = blockIdx.x;
  int g = sb / nsb_c, lsb = sb - g * nsb_c;
  int n0 = g * Nc + (lsb << NS_SH);
  int nn = min(NS, min(Nc - (lsb << NS_SH), N - n0));
  if (nn <= 0) return;
  for (int t = threadIdx.x; t < NS; t += TPB) hist[t] = 0;
  __syncthreads();
  int cnt = scnt[sb];
  const int2* pp = pair2 + sbase[sb];
  for (int i = threadIdx.x; i < cnt; i += TPB) atomicAdd(&hist[pp[i].x - n0], 1);
  __syncthreads();
  for (int t = threadIdx.x; t < nn; t += TPB) degi[n0 + t] = hist[t];
}

// inclusive block scan; emit per-block sums
__global__ void k_scan1(const int* __restrict__ degi, int* __restrict__ incl,
                        int* __restrict__ bsums, int n) {
  __shared__ int s[TPB];
  int i = blockIdx.x * TPB + threadIdx.x;
  int v = (i < n) ? degi[i] : 0;
  s[threadIdx.x] = v;
  __syncthreads();
#pragma unroll
  for (int off = 1; off < TPB; off <<= 1) {
    int t = (threadIdx.x >= off) ? s[threadIdx.x - off] : 0;
    __syncthreads();
    s[threadIdx.x] += t;
    __syncthreads();
  }
  if (i < n) incl[i] = s[threadIdx.x];
  if (threadIdx.x == TPB - 1) bsums[blockIdx.x] = s[TPB - 1];
}

// single-block exclusive scan of block sums (nb <= 1024)
__global__ void k_scan2(int* __restrict__ bsums, int nb) {
  __shared__ int s[1024];
  int t = threadIdx.x;
  int v = (t < nb) ? bsums[t] : 0;
  s[t] = v;
  __syncthreads();
#pragma unroll
  for (int off = 1; off < 1024; off <<= 1) {
    int u = (t >= off) ? s[t - off] : 0;
    __syncthreads();
    s[t] += u;
    __syncthreads();
  }
  if (t < nb) bsums[t] = s[t] - v;  // exclusive
}

// starts/cursor + dinv + packed meta {start, deg, dinv_bits, 0}
__global__ void k_finalize(const int* __restrict__ degi, const int* __restrict__ incl,
                           const int* __restrict__ bsums, int* __restrict__ cursor,
                           float* __restrict__ dinv, int4* __restrict__ meta, int n) {
  int i = blockIdx.x * TPB + threadIdx.x;
  if (i >= n) return;
  int dg = degi[i];
  int st = bsums[blockIdx.x] + incl[i] - dg;
  float di = rsqrtf((float)(dg + 1));  // +1 self-loop
  cursor[i] = st;
  dinv[i] = di;
  meta[i] = make_int4(st, dg, __float_as_int(di), 0);
}

// ---------- sort3: per-sub-bucket counting sort, emit ssrc coalesced ----------
__global__ void k_sort3(const int* __restrict__ scnt, const int* __restrict__ sbase,
                        const int2* __restrict__ pair2, const int4* __restrict__ meta,
                        int* __restrict__ cursor, int* __restrict__ ssrc,
                        int nsb_c, int Nc, int N) {
  __shared__ int st[NS];
  __shared__ int curi[NS];
  __shared__ int ss[CAP3];
  int sb = blockIdx.x;
  int g = sb / nsb_c, lsb = sb - g * nsb_c;
  int n0 = g * Nc + (lsb << NS_SH);
  int nn = min(NS, min(Nc - (lsb << NS_SH), N - n0));
  if (nn <= 0) return;
  int cnt = scnt[sb];
  if (cnt == 0) return;
  const int2* pp = pair2 + sbase[sb];
  if (cnt <= CAP3) {
    for (int t = threadIdx.x; t < nn; t += TPB) {
      st[t] = meta[n0 + t].x;
      curi[t] = 0;
    }
    __syncthreads();
    int base0 = st[0];
    for (int i = threadIdx.x; i < cnt; i += TPB) {
      int2 pr = pp[i];
      int l = pr.x - n0;
      int r = atomicAdd(&curi[l], 1);
      ss[(st[l] - base0) + r] = pr.y;
    }
    __syncthreads();
    for (int i = threadIdx.x; i < cnt; i += TPB) ssrc[base0 + i] = ss[i];
  } else {
    // overflow fallback (statistically unreachable for uniform dst)
    for (int i = threadIdx.x; i < cnt; i += TPB) {
      int2 pr = pp[i];
      int pos = atomicAdd(&cursor[pr.x], 1);
      ssrc[pos] = pr.y;
    }
  }
}

// ---------- gx = x * dinv (16 channels) ----------
__global__ void k_prescale16(const float* __restrict__ x, const float* __restrict__ dinv,
                             float* __restrict__ gx, int n4) {
  int gid = blockIdx.x * blockDim.x + threadIdx.x;
  if (gid >= n4) return;
  int i = gid >> 2;
  float di = dinv[i];
  float4 v = reinterpret_cast<const float4*>(x)[gid];
  v.x *= di; v.y *= di; v.z *= di; v.w *= di;
  reinterpret_cast<float4*>(gx)[gid] = v;
}

// ---------- gather: 4 threads/dst; out = dinv[d]*(v[d] + sum_edges v[src]) ----------
template <int CH>
__global__ void k_gatherT(const int4* __restrict__ meta, const int* __restrict__ ssrc,
                          const float* __restrict__ v, float* __restrict__ outp, int n) {
  int gid = blockIdx.x * blockDim.x + threadIdx.x;
  int dst = gid >> 2;
  int q = gid & 3;
  if (dst >= n) return;
  int4 md = meta[dst];
  int s0 = md.x;
  int dg = md.y;
  float dd = __int_as_float(md.z);
  size_t o0 = (size_t)q * 4;
  size_t o1 = o0 + 16;
  const float* rd = v + (size_t)dst * CH;
  float4 a0 = *reinterpret_cast<const float4*>(rd + o0);   // self term
  float4 a1;
  if (CH == 32) a1 = *reinterpret_cast<const float4*>(rd + o1);
  int j = 0;
  for (; j + 2 <= dg; j += 2) {
    int s1 = __builtin_nontemporal_load(&ssrc[s0 + j]);
    int s2 = __builtin_nontemporal_load(&ssrc[s0 + j + 1]);
    const float* r1 = v + (size_t)s1 * CH;
    const float* r2 = v + (size_t)s2 * CH;
    float4 v0 = *reinterpret_cast<const float4*>(r1 + o0);
    float4 w0 = *reinterpret_cast<const float4*>(r2 + o0);
    a0.x += v0.x + w0.x; a0.y += v0.y + w0.y; a0.z += v0.z + w0.z; a0.w += v0.w + w0.w;
    if (CH == 32) {
      float4 v1 = *reinterpret_cast<const float4*>(r1 + o1);
      float4 w1 = *reinterpret_cast<const float4*>(r2 + o1);
      a1.x += v1.x + w1.x; a1.y += v1.y + w1.y; a1.z += v1.z + w1.z; a1.w += v1.w + w1.w;
    }
  }
  if (j < dg) {
    int s1 = __builtin_nontemporal_load(&ssrc[s0 + j]);
    const float* r1 = v + (size_t)s1 * CH;
    float4 v0 = *reinterpret_cast<const float4*>(r1 + o0);
    a0.x += v0.x; a0.y += v0.y; a0.z += v0.z; a0.w += v0.w;
    if (CH == 32) {
      float4 v1 = *reinterpret_cast<const float4*>(r1 + o1);
      a1.x += v1.x; a1.y += v1.y; a1.z += v1.z; a1.w += v1.w;
    }
  }
  a0.x *= dd; a0.y *= dd; a0.z *= dd; a0.w *= dd;
  float* wr = outp + (size_t)dst * CH;
  *reinterpret_cast<float4*>(wr + o0) = a0;
  if (CH == 32) {
    a1.x *= dd; a1.y *= dd; a1.z *= dd; a1.w *= dd;
    *reinterpret_cast<float4*>(wr + o1) = a1;
  }
}

// ---------- transform: out = (h @ W + b) [relu] [* dinv] ----------
template <int IN, int OUT, bool RELU, bool PRESCALE>
__global__ void k_transform(const float* __restrict__ h, const float* __restrict__ W,
                            const float* __restrict__ b, const float* __restrict__ dinv,
                            float* __restrict__ outp, int n) {
  __shared__ float sW[IN * OUT];
  __shared__ float sB[OUT];
  for (int t = threadIdx.x; t < IN * OUT; t += blockDim.x) sW[t] = W[t];
  if (threadIdx.x < OUT) sB[threadIdx.x] = b[threadIdx.x];
  __syncthreads();
  int i = blockIdx.x * blockDim.x + threadIdx.x;
  if (i >= n) return;
  float xr[IN];
  const float4* hp = reinterpret_cast<const float4*>(h + (size_t)i * IN);
#pragma unroll
  for (int k4 = 0; k4 < IN / 4; ++k4) {
    float4 v = hp[k4];
    xr[k4 * 4 + 0] = v.x; xr[k4 * 4 + 1] = v.y;
    xr[k4 * 4 + 2] = v.z; xr[k4 * 4 + 3] = v.w;
  }
  float acc[OUT];
#pragma unroll
  for (int c = 0; c < OUT; ++c) acc[c] = sB[c];
#pragma unroll
  for (int k = 0; k < IN; ++k) {
    float xv = xr[k];
#pragma unroll
    for (int c = 0; c < OUT; ++c) acc[c] = fmaf(xv, sW[k * OUT + c], acc[c]);
  }
  float di = PRESCALE ? dinv[i] : 1.0f;
  float4* mp = reinterpret_cast<float4*>(outp + (size_t)i * OUT);
#pragma unroll
  for (int c4 = 0; c4 < OUT / 4; ++c4) {
    float4 o;
    o.x = acc[c4 * 4 + 0]; o.y = acc[c4 * 4 + 1];
    o.z = acc[c4 * 4 + 2]; o.w = acc[c4 * 4 + 3];
    if (RELU) {
      o.x = fmaxf(o.x, 0.0f); o.y = fmaxf(o.y, 0.0f);
      o.z = fmaxf(o.z, 0.0f); o.w = fmaxf(o.w, 0.0f);
    }
    if (PRESCALE) { o.x *= di; o.y *= di; o.z *= di; o.w *= di; }
    mp[c4] = o;
  }
}

extern "C" void kernel_launch(void* const* d_in, const int* in_sizes, int n_in,
                              void* d_out, int out_size, void* d_ws, size_t ws_size,
                              hipStream_t stream) {
  const float* x  = (const float*)d_in[0];
  const void*  ei = d_in[1];
  const float* W1 = (const float*)d_in[2];
  const float* b1 = (const float*)d_in[3];
  const float* W2 = (const float*)d_in[4];
  const float* b2 = (const float*)d_in[5];
  float* out = (float*)d_out;

  const int N = in_sizes[0] / 16;
  const int E = in_sizes[1] / 2;
  const int Nc = (N + 7) / 8;               // 25000
  const int nsb_c = (Nc + NS - 1) / NS;     // 196 sub-buckets per chunk
  const int NSB = 8 * nsb_c;                // 1568

  // workspace carve-up (256B aligned)
  char* p = (char*)d_ws;
  auto alloc = [&](size_t bytes) {
    char* r = p;
    p += (bytes + 255) & ~(size_t)255;
    return r;
  };
  int*   flag   = (int*)alloc(4);
  float* dinv   = (float*)alloc((size_t)N * 4);
  int*   degi   = (int*)alloc((size_t)N * 4);
  int*   incl   = (int*)alloc((size_t)N * 4);
  int*   cursor = (int*)alloc((size_t)N * 4);
  int4*  meta   = (int4*)alloc((size_t)N * 16);
  int*   bsums  = (int*)alloc(4096);
  int*   cum    = (int*)alloc(64);
  int*   ccnt   = (int*)alloc(64);
  int*   cbase  = (int*)alloc(64);
  int*   gtail  = (int*)alloc(64);
  int*   scnt   = (int*)alloc((size_t)NSB * 4);
  int*   sbase  = (int*)alloc((size_t)NSB * 4);
  int*   stail  = (int*)alloc((size_t)NSB * 4);
  int*   ssrc   = (int*)alloc((size_t)E * 4);
  float* bufA   = (float*)alloc((size_t)N * 32 * 4);   // pair -> gx -> gh
  float* bufB   = (float*)alloc((size_t)N * 32 * 4);   // pair2 -> agg1 -> agg2
  // lifetimes: pair(bufA) dies at k_place2; pair2(bufB) dies at k_sort3
  //            (before gather writes agg1 into bufB).
  unsigned long long* pairW  = (unsigned long long*)bufA;
  const int2*         pairR  = (const int2*)bufA;
  unsigned long long* pair2W = (unsigned long long*)bufB;
  const int2*         pair2R = (const int2*)bufB;
  float* gx   = bufA;
  float* agg1 = bufB;
  float* gh   = bufA;
  float* agg2 = bufB;

  const int gN  = (N + TPB - 1) / TPB;
  const int gN4 = (N * 4 + TPB - 1) / TPB;
  const int gBk = (E + BEB - 1) / BEB;
  const int gSc = ((E + SEB - 1) / SEB) * 8;   // scnt (idle blocks early-exit)
  const int gP2 = ((E + PEB - 1) / PEB) * 8;   // place2

  // 0. index-width detect + zero cum
  k_detect_i64<<<1, TPB, 0, stream>>>((const unsigned int*)ei, E, flag, cum);
  // 1. chunk counts -> bases; zero sub-bucket counts
  k_count8<<<512, TPB, 0, stream>>>(ei, flag, cum, E, Nc);
  k_cbase<<<1, 64, 0, stream>>>(cum, ccnt, cbase, gtail, E);
  k_zero_i<<<(NSB + TPB - 1) / TPB, TPB, 0, stream>>>(scnt, NSB);
  // 2. level-1 bucket (ballot-aggregated)
  k_bucket<<<gBk, TPB, 0, stream>>>(ei, flag, gtail, pairW, E, Nc);
  // 3. sub-bucket counts -> bases
  k_scnt<<<gSc, TPB, 0, stream>>>(cbase, ccnt, pairR, scnt, nsb_c, Nc);
  k_sbase<<<1, 1024, 0, stream>>>(scnt, sbase, stail, NSB);
  // 4. level-2 place (coalesced run emission)
  k_place2<<<gP2, TPB, 0, stream>>>(cbase, ccnt, pairW, stail, pair2W, nsb_c, Nc);
  // 5. degi (coalesced) -> scans -> meta/cursor
  k_hist3<<<NSB, TPB, 0, stream>>>(scnt, sbase, pair2R, degi, nsb_c, Nc, N);
  k_scan1<<<gN, TPB, 0, stream>>>(degi, incl, bsums, N);
  k_scan2<<<1, 1024, 0, stream>>>(bsums, gN);
  k_finalize<<<gN, TPB, 0, stream>>>(degi, incl, bsums, cursor, dinv, meta, N);
  // 6. CSR fill via per-sub-bucket LDS counting sort (coalesced ssrc)
  k_sort3<<<NSB, TPB, 0, stream>>>(scnt, sbase, pair2R, meta, cursor, ssrc, nsb_c, Nc, N);
  // 7. layer 1: aggregate in 16-dim input space, then transform
  k_prescale16<<<gN4, TPB, 0, stream>>>(x, dinv, gx, N * 4);
  k_gatherT<16><<<gN4, TPB, 0, stream>>>(meta, ssrc, gx, agg1, N);
  k_transform<16, 32, true, true><<<gN, TPB, 0, stream>>>(agg1, W1, b1, dinv, gh, N);
  // 8. layer 2: aggregate 32-dim, then transform -> out
  k_gatherT<32><<<gN4, TPB, 0, stream>>>(meta, ssrc, gh, agg2, N);
  k_transform<32, 32, false, false><<<gN, TPB, 0, stream>>>(agg2, W2, b2, dinv, out, N);
}

// Round 10
// 320.700 us; speedup vs baseline: 1.8216x; 1.0594x over previous
//
#include <hip/hip_runtime.h>

#define TPB 256
#define TPG 512    // threads per fused-gather / prep block
#define BEB 2048   // edges per level-1 bucket block
#define SEB 2048   // edges per scnt slab
#define PEB 8192   // edges per place2 slab
#define NS_SH 7    // 128 nodes per sub-bucket
#define NS (1 << NS_SH)
#define CAP 2560   // fused-gather LDS edge capacity (mean 1536, +26 sigma)

// ---------- index-width detect + zero cum counters ----------
__global__ void k_detect_i64(const unsigned int* __restrict__ ei, int E,
                             int* __restrict__ flag, int* __restrict__ cum) {
  __shared__ int nz;
  if (threadIdx.x == 0) nz = 0;
  if (threadIdx.x < 7) cum[threadIdx.x] = 0;
  __syncthreads();
  int step = E / 4096;
  if (step < 1) step = 1;
  for (int t = threadIdx.x; t < 4096; t += blockDim.x) {
    long long pos = 1 + 2LL * (long long)t * step;   // odd dword positions
    if (pos < 2LL * (long long)E && ei[pos] != 0u) atomicAdd(&nz, 1);
  }
  __syncthreads();
  if (threadIdx.x == 0) *flag = (nz == 0) ? 1 : 0;
}

__device__ __forceinline__ int load_idx(const void* __restrict__ p, long long pos,
                                        int is64) {
  if (is64) return (int)(((const long long*)p)[pos]);
  return ((const int*)p)[pos];
}

__global__ void k_zero_i(int* __restrict__ p, int n) {
  int i = blockIdx.x * blockDim.x + threadIdx.x;
  if (i < n) p[i] = 0;
}

// ---------- cumulative chunk counts: cum[k] = #(d < (k+1)*Nc) ----------
__global__ void k_count8(const void* __restrict__ ei, const int* __restrict__ flag,
                         int* __restrict__ cum, int E, int Nc) {
  int is64 = *flag;
  int c[7] = {0, 0, 0, 0, 0, 0, 0};
  int stride = gridDim.x * blockDim.x;
  for (int e = blockIdx.x * blockDim.x + threadIdx.x; e < E; e += stride) {
    int d = load_idx(ei, (long long)E + e, is64);
#pragma unroll
    for (int k = 0; k < 7; ++k) c[k] += (d < (k + 1) * Nc) ? 1 : 0;
  }
#pragma unroll
  for (int k = 0; k < 7; ++k)
#pragma unroll
    for (int off = 32; off >= 1; off >>= 1) c[k] += __shfl_xor(c[k], off);
  __shared__ int red[4][7];
  int lane = threadIdx.x & 63, wid = threadIdx.x >> 6;
  if (lane == 0) {
#pragma unroll
    for (int k = 0; k < 7; ++k) red[wid][k] = c[k];
  }
  __syncthreads();
  if (threadIdx.x < 7) {
    int s = red[0][threadIdx.x] + red[1][threadIdx.x] +
            red[2][threadIdx.x] + red[3][threadIdx.x];
    if (s) atomicAdd(&cum[threadIdx.x], s);
  }
}

// cum -> per-chunk counts, bases, fill tails
__global__ void k_cbase(const int* __restrict__ cum, int* __restrict__ ccnt,
                        int* __restrict__ cbase, int* __restrict__ gtail, int E) {
  if (threadIdx.x == 0) {
    int prev = 0, acc = 0;
    for (int g = 0; g < 8; ++g) {
      int cg = ((g < 7) ? cum[g] : E) - prev;
      prev = (g < 7) ? cum[g] : E;
      ccnt[g] = cg;
      cbase[g] = acc;
      gtail[g] = acc;
      acc += cg;
    }
  }
}

// ---------- level-1 bucket: chunk-grouped packed (d,s) pairs ----------
__global__ void k_bucket(const void* __restrict__ ei, const int* __restrict__ flag,
                         int* __restrict__ gtail, unsigned long long* __restrict__ pair,
                         int E, int Nc) {
  __shared__ int sd[BEB], ss[BEB];
  __shared__ int bbase[8], cur[8];
  __shared__ int red[4][7];
  int is64 = *flag;
  int base = blockIdx.x * BEB;
  int cnt = min(BEB, E - base);
  int c[7] = {0, 0, 0, 0, 0, 0, 0};
  for (int i = threadIdx.x; i < cnt; i += TPB) {
    int e = base + i;
    int d = load_idx(ei, (long long)E + e, is64);
    int s = load_idx(ei, e, is64);
    sd[i] = d;
    ss[i] = s;
#pragma unroll
    for (int k = 0; k < 7; ++k) c[k] += (d < (k + 1) * Nc) ? 1 : 0;
  }
#pragma unroll
  for (int k = 0; k < 7; ++k)
#pragma unroll
    for (int off = 32; off >= 1; off >>= 1) c[k] += __shfl_xor(c[k], off);
  int lane = threadIdx.x & 63, wid = threadIdx.x >> 6;
  if (lane == 0) {
#pragma unroll
    for (int k = 0; k < 7; ++k) red[wid][k] = c[k];
  }
  __syncthreads();
  if (threadIdx.x < 8) {
    int g = threadIdx.x;
    int hi = (g < 7) ? (red[0][g] + red[1][g] + red[2][g] + red[3][g]) : cnt;
    int lo = (g > 0) ? (red[0][g - 1] + red[1][g - 1] + red[2][g - 1] + red[3][g - 1]) : 0;
    bbase[g] = atomicAdd(&gtail[g], hi - lo);
    cur[g] = 0;
  }
  __syncthreads();
  int trips = (cnt + TPB - 1) / TPB;
  unsigned long long lt = (1ULL << lane) - 1ULL;
  for (int t = 0; t < trips; ++t) {
    int i = t * TPB + threadIdx.x;
    bool act = i < cnt;
    int d = act ? sd[i] : 0;
    int s = act ? ss[i] : 0;
    int g = 0;
#pragma unroll
    for (int k = 1; k <= 7; ++k) g += (d >= k * Nc) ? 1 : 0;
    unsigned long long m0 = __ballot(act && g == 0);
    unsigned long long m1 = __ballot(act && g == 1);
    unsigned long long m2 = __ballot(act && g == 2);
    unsigned long long m3 = __ballot(act && g == 3);
    unsigned long long m4 = __ballot(act && g == 4);
    unsigned long long m5 = __ballot(act && g == 5);
    unsigned long long m6 = __ballot(act && g == 6);
    unsigned long long m7 = __ballot(act && g == 7);
    int wb = 0;
    if (lane < 8) {
      unsigned long long mm =
          lane < 4 ? (lane < 2 ? (lane == 0 ? m0 : m1) : (lane == 2 ? m2 : m3))
                   : (lane < 6 ? (lane == 4 ? m4 : m5) : (lane == 6 ? m6 : m7));
      wb = atomicAdd(&cur[lane], (int)__popcll(mm));
    }
    int mybase = __shfl(wb, g);
    unsigned long long mk =
        g < 4 ? (g < 2 ? (g == 0 ? m0 : m1) : (g == 2 ? m2 : m3))
              : (g < 6 ? (g == 4 ? m4 : m5) : (g == 6 ? m6 : m7));
    int rank = (int)__popcll(mk & lt);
    if (act) {
      int pos = bbase[g] + mybase + rank;
      unsigned long long pk =
          ((unsigned long long)(unsigned)s << 32) | (unsigned)d;
      __builtin_nontemporal_store(pk, &pair[pos]);
    }
  }
}

// ---------- sub-bucket counts ----------
__global__ void k_scnt(const int* __restrict__ cbase, const int* __restrict__ ccnt,
                       const int2* __restrict__ pair, int* __restrict__ scnt,
                       int nsb_c, int Nc) {
  __shared__ int hist[256];
  for (int t = threadIdx.x; t < nsb_c; t += TPB) hist[t] = 0;
  __syncthreads();
  int g = blockIdx.x & 7, seg = blockIdx.x >> 3;
  int cnt = ccnt[g];
  int base = seg * SEB;
  if (base < cnt) {
    int lim = min(base + SEB, cnt);
    const int2* pp = pair + cbase[g];
    int lo = g * Nc;
    for (int i = base + threadIdx.x; i < lim; i += TPB)
      atomicAdd(&hist[(pp[i].x - lo) >> NS_SH], 1);
  }
  __syncthreads();
  for (int t = threadIdx.x; t < nsb_c; t += TPB)
    if (hist[t]) atomicAdd(&scnt[g * nsb_c + t], hist[t]);
}

// ---------- exclusive scan of nsb (<=2048) sub-bucket counts ----------
__global__ void k_sbase(const int* __restrict__ scnt, int* __restrict__ sbase,
                        int* __restrict__ stail, int nsb) {
  __shared__ int p[1024];
  int t = threadIdx.x;  // 1024 threads
  int i0 = 2 * t, i1 = 2 * t + 1;
  int v0 = (i0 < nsb) ? scnt[i0] : 0;
  int v1 = (i1 < nsb) ? scnt[i1] : 0;
  p[t] = v0 + v1;
  __syncthreads();
#pragma unroll
  for (int off = 1; off < 1024; off <<= 1) {
    int u = (t >= off) ? p[t - off] : 0;
    __syncthreads();
    p[t] += u;
    __syncthreads();
  }
  int excl = p[t] - (v0 + v1);
  if (i0 < nsb) { sbase[i0] = excl; stail[i0] = excl; }
  if (i1 < nsb) { sbase[i1] = excl + v0; stail[i1] = excl + v0; }
}

// ---------- place2: sort slab by sub-bucket, emit packed (src<<7|local) runs ----------
__global__ void k_place2(const int* __restrict__ cbase, const int* __restrict__ ccnt,
                         const unsigned long long* __restrict__ pair,
                         int* __restrict__ stail, int* __restrict__ pair2,
                         int nsb_c, int Nc) {
  __shared__ int sorted[PEB];
  __shared__ int hist[256], bb[256], gb[256], cur[256];
  int g = blockIdx.x & 7, seg = blockIdx.x >> 3;
  int cnt = ccnt[g];
  int base = seg * PEB;
  if (base >= cnt) return;  // block-uniform
  int lim = min(base + PEB, cnt);
  int lo = g * Nc;
  const unsigned long long* pp = pair + cbase[g];
  for (int t = threadIdx.x; t < 256; t += TPB) hist[t] = 0;
  __syncthreads();
  // pass 1: count
  for (int i = base + threadIdx.x; i < lim; i += TPB) {
    int d = (int)(unsigned)(pp[i] & 0xffffffffULL);
    atomicAdd(&hist[(d - lo) >> NS_SH], 1);
  }
  __syncthreads();
  // exclusive scan hist -> bb
  {
    int t = threadIdx.x;
    int v = hist[t];
    bb[t] = v;
    __syncthreads();
#pragma unroll
    for (int off = 1; off < 256; off <<= 1) {
      int u = (t >= off) ? bb[t - off] : 0;
      __syncthreads();
      bb[t] += u;
      __syncthreads();
    }
    bb[t] -= v;
  }
  // reserve global space per sub-bucket
  for (int t = threadIdx.x; t < nsb_c; t += TPB) {
    gb[t] = hist[t] ? atomicAdd(&stail[g * nsb_c + t], hist[t]) : 0;
    cur[t] = 0;
  }
  __syncthreads();
  // pass 2: sort packed values into LDS
  for (int i = base + threadIdx.x; i < lim; i += TPB) {
    unsigned long long pk = pp[i];
    int d = (int)(unsigned)(pk & 0xffffffffULL);
    int rel = d - lo;
    int sb = rel >> NS_SH;
    int packed = ((int)(pk >> 32) << NS_SH) | (rel & (NS - 1));
    int r = atomicAdd(&cur[sb], 1);
    sorted[bb[sb] + r] = packed;
  }
  __syncthreads();
  // emit: linear over sorted -> contiguous runs per sub-bucket
  int n = lim - base;
  for (int i = threadIdx.x; i < n; i += TPB) {
    int packed = sorted[i];
    // recover sub-bucket from position via bb: use binary search-free trick:
    // local sb = high bits of... we stored only local; find sb by bb search.
    // Instead: recompute from packed? packed has only local 7 bits. Do a
    // small scan: since bb is sorted ascending (256 entries), binary search.
    int loi = 0, hii = nsb_c;  // find last sb with bb[sb] <= i
    while (hii - loi > 1) {
      int mid = (loi + hii) >> 1;
      if (bb[mid] <= i) loi = mid; else hii = mid;
    }
    pair2[gb[loi] + (i - bb[loi])] = packed;
  }
}

// ---------- prep: per sub-bucket deg->dinv, gx = x*dinv (coalesced) ----------
__global__ void k_prep(const int* __restrict__ scnt, const int* __restrict__ sbase,
                       const int* __restrict__ pair2, const float* __restrict__ x,
                       float* __restrict__ dinv, float* __restrict__ gx,
                       int nsb_c, int Nc, int N) {
  __shared__ int hist[NS];
  __shared__ float sdi[NS];
  int sb = blockIdx.x;
  int g = sb / nsb_c, lsb = sb - g * nsb_c;
  int n0 = g * Nc + (lsb << NS_SH);
  int nn = min(NS, min(Nc - (lsb << NS_SH), N - n0));
  if (nn <= 0) return;
  for (int t = threadIdx.x; t < NS; t += TPG) hist[t] = 0;
  __syncthreads();
  int cnt = scnt[sb];
  const int* pp = pair2 + sbase[sb];
  for (int i = threadIdx.x; i < cnt; i += TPG)
    atomicAdd(&hist[pp[i] & (NS - 1)], 1);
  __syncthreads();
  for (int t = threadIdx.x; t < nn; t += TPG) {
    float di = rsqrtf((float)(hist[t] + 1));
    sdi[t] = di;
    dinv[n0 + t] = di;
  }
  __syncthreads();
  int tot = nn * 16;
  const float* xb = x + (size_t)n0 * 16;
  float* gb_ = gx + (size_t)n0 * 16;
  for (int idx = threadIdx.x; idx < tot; idx += TPG)
    gb_[idx] = xb[idx] * sdi[idx >> 4];
}

// ---------- fused sort+gather per sub-bucket ----------
// agg[d] = dinv[d] * (v[d] + sum_{e:dst=d} v[src_e]);  4 threads per dst.
template <int CH>
__global__ void k_gatherF(const int* __restrict__ scnt, const int* __restrict__ sbase,
                          const int* __restrict__ pair2, const float* __restrict__ dinv,
                          const float* __restrict__ v, float* __restrict__ agg,
                          int nsb_c, int Nc, int N) {
  __shared__ int hist[NS], bb[NS], cur[NS];
  __shared__ int sl[CAP];
  int sb = blockIdx.x;
  int g = sb / nsb_c, lsb = sb - g * nsb_c;
  int n0 = g * Nc + (lsb << NS_SH);
  int nn = min(NS, min(Nc - (lsb << NS_SH), N - n0));
  if (nn <= 0) return;
  int cnt = scnt[sb];
  const int* pp = pair2 + sbase[sb];
  int tid = threadIdx.x;
  if (cnt <= CAP) {
    for (int t = tid; t < NS; t += TPG) { hist[t] = 0; cur[t] = 0; }
    __syncthreads();
    for (int i = tid; i < cnt; i += TPG) atomicAdd(&hist[pp[i] & (NS - 1)], 1);
    __syncthreads();
    if (tid < NS) bb[tid] = hist[tid];
    __syncthreads();
#pragma unroll
    for (int off = 1; off < NS; off <<= 1) {
      int u = (tid < NS && tid >= off) ? bb[tid - off] : 0;
      __syncthreads();
      if (tid < NS) bb[tid] += u;
      __syncthreads();
    }
    if (tid < NS) bb[tid] -= hist[tid];  // exclusive
    __syncthreads();
    for (int i = tid; i < cnt; i += TPG) {
      int pk = pp[i];
      int l = pk & (NS - 1);
      int r = atomicAdd(&cur[l], 1);
      sl[bb[l] + r] = pk >> NS_SH;
    }
    __syncthreads();
    int grp = tid >> 2, q = tid & 3;
    if (grp < nn) {
      int dst = n0 + grp;
      float dd = dinv[dst];
      int s0 = bb[grp], dg = hist[grp];
      size_t o0 = (size_t)q * 4;
      size_t o1 = o0 + 16;
      const float* rd = v + (size_t)dst * CH;
      float4 a0 = *reinterpret_cast<const float4*>(rd + o0);  // self term
      float4 a1;
      if (CH == 32) a1 = *reinterpret_cast<const float4*>(rd + o1);
      int j = 0;
      for (; j + 2 <= dg; j += 2) {
        int s1 = sl[s0 + j];
        int s2 = sl[s0 + j + 1];
        const float* r1 = v + (size_t)s1 * CH;
        const float* r2 = v + (size_t)s2 * CH;
        float4 v0 = *reinterpret_cast<const float4*>(r1 + o0);
        float4 w0 = *reinterpret_cast<const float4*>(r2 + o0);
        a0.x += v0.x + w0.x; a0.y += v0.y + w0.y;
        a0.z += v0.z + w0.z; a0.w += v0.w + w0.w;
        if (CH == 32) {
          float4 v1 = *reinterpret_cast<const float4*>(r1 + o1);
          float4 w1 = *reinterpret_cast<const float4*>(r2 + o1);
          a1.x += v1.x + w1.x; a1.y += v1.y + w1.y;
          a1.z += v1.z + w1.z; a1.w += v1.w + w1.w;
        }
      }
      if (j < dg) {
        int s1 = sl[s0 + j];
        const float* r1 = v + (size_t)s1 * CH;
        float4 v0 = *reinterpret_cast<const float4*>(r1 + o0);
        a0.x += v0.x; a0.y += v0.y; a0.z += v0.z; a0.w += v0.w;
        if (CH == 32) {
          float4 v1 = *reinterpret_cast<const float4*>(r1 + o1);
          a1.x += v1.x; a1.y += v1.y; a1.z += v1.z; a1.w += v1.w;
        }
      }
      a0.x *= dd; a0.y *= dd; a0.z *= dd; a0.w *= dd;
      float* wr = agg + (size_t)dst * CH;
      *reinterpret_cast<float4*>(wr + o0) = a0;
      if (CH == 32) {
        a1.x *= dd; a1.y *= dd; a1.z *= dd; a1.w *= dd;
        *reinterpret_cast<float4*>(wr + o1) = a1;
      }
    }
  } else {
    // fallback (statistically unreachable): self-init then fp32 atomics
    for (int idx = tid; idx < nn * CH; idx += TPG) {
      int l = idx / CH, c = idx - l * CH;
      float dd = dinv[n0 + l];
      agg[(size_t)(n0 + l) * CH + c] = v[(size_t)(n0 + l) * CH + c] * dd;
    }
    __syncthreads();
    for (int i = tid; i < cnt; i += TPG) {
      int pk = pp[i];
      int l = pk & (NS - 1);
      int s = pk >> NS_SH;
      float dd = dinv[n0 + l];
      for (int c = 0; c < CH; ++c)
        atomicAdd(&agg[(size_t)(n0 + l) * CH + c], v[(size_t)s * CH + c] * dd);
    }
  }
}

// ---------- transform: out = (h @ W + b) [relu] [* dinv] ----------
template <int IN, int OUT, bool RELU, bool PRESCALE>
__global__ void k_transform(const float* __restrict__ h, const float* __restrict__ W,
                            const float* __restrict__ b, const float* __restrict__ dinv,
                            float* __restrict__ outp, int n) {
  __shared__ float sW[IN * OUT];
  __shared__ float sB[OUT];
  for (int t = threadIdx.x; t < IN * OUT; t += blockDim.x) sW[t] = W[t];
  if (threadIdx.x < OUT) sB[threadIdx.x] = b[threadIdx.x];
  __syncthreads();
  int i = blockIdx.x * blockDim.x + threadIdx.x;
  if (i >= n) return;
  float xr[IN];
  const float4* hp = reinterpret_cast<const float4*>(h + (size_t)i * IN);
#pragma unroll
  for (int k4 = 0; k4 < IN / 4; ++k4) {
    float4 v = hp[k4];
    xr[k4 * 4 + 0] = v.x; xr[k4 * 4 + 1] = v.y;
    xr[k4 * 4 + 2] = v.z; xr[k4 * 4 + 3] = v.w;
  }
  float acc[OUT];
#pragma unroll
  for (int c = 0; c < OUT; ++c) acc[c] = sB[c];
#pragma unroll
  for (int k = 0; k < IN; ++k) {
    float xv = xr[k];
#pragma unroll
    for (int c = 0; c < OUT; ++c) acc[c] = fmaf(xv, sW[k * OUT + c], acc[c]);
  }
  float di = PRESCALE ? dinv[i] : 1.0f;
  float4* mp = reinterpret_cast<float4*>(outp + (size_t)i * OUT);
#pragma unroll
  for (int c4 = 0; c4 < OUT / 4; ++c4) {
    float4 o;
    o.x = acc[c4 * 4 + 0]; o.y = acc[c4 * 4 + 1];
    o.z = acc[c4 * 4 + 2]; o.w = acc[c4 * 4 + 3];
    if (RELU) {
      o.x = fmaxf(o.x, 0.0f); o.y = fmaxf(o.y, 0.0f);
      o.z = fmaxf(o.z, 0.0f); o.w = fmaxf(o.w, 0.0f);
    }
    if (PRESCALE) { o.x *= di; o.y *= di; o.z *= di; o.w *= di; }
    mp[c4] = o;
  }
}

extern "C" void kernel_launch(void* const* d_in, const int* in_sizes, int n_in,
                              void* d_out, int out_size, void* d_ws, size_t ws_size,
                              hipStream_t stream) {
  const float* x  = (const float*)d_in[0];
  const void*  ei = d_in[1];
  const float* W1 = (const float*)d_in[2];
  const float* b1 = (const float*)d_in[3];
  const float* W2 = (const float*)d_in[4];
  const float* b2 = (const float*)d_in[5];
  float* out = (float*)d_out;

  const int N = in_sizes[0] / 16;
  const int E = in_sizes[1] / 2;
  const int Nc = (N + 7) / 8;               // 25000
  const int nsb_c = (Nc + NS - 1) / NS;     // 196 sub-buckets per chunk
  const int NSB = 8 * nsb_c;                // 1568

  // workspace carve-up (256B aligned)
  char* p = (char*)d_ws;
  auto alloc = [&](size_t bytes) {
    char* r = p;
    p += (bytes + 255) & ~(size_t)255;
    return r;
  };
  int*   flag  = (int*)alloc(4);
  float* dinv  = (float*)alloc((size_t)N * 4);
  int*   cum   = (int*)alloc(64);
  int*   ccnt  = (int*)alloc(64);
  int*   cbase = (int*)alloc(64);
  int*   gtail = (int*)alloc(64);
  int*   scnt  = (int*)alloc((size_t)NSB * 4);
  int*   sbase = (int*)alloc((size_t)NSB * 4);
  int*   stail = (int*)alloc((size_t)NSB * 4);
  int*   pair2 = (int*)alloc((size_t)E * 4);           // packed (src<<7)|local
  float* bufA  = (float*)alloc((size_t)N * 32 * 4);    // pair -> gx+agg1 -> agg2
  float* bufC  = (float*)alloc((size_t)N * 32 * 4);    // gh
  // lifetimes: pair(bufA,19.2MB) dies at k_place2; then bufA = gx(12.8)|agg1(12.8);
  // both die at transform1; then agg2 = bufA. pair2 lives to gatherF<32>.
  unsigned long long* pairW = (unsigned long long*)bufA;
  const int2*         pairR = (const int2*)bufA;
  float* gx   = bufA;
  float* agg1 = bufA + (size_t)N * 16;
  float* gh   = bufC;
  float* agg2 = bufA;

  const int gN  = (N + TPB - 1) / TPB;
  const int gBk = (E + BEB - 1) / BEB;
  const int gSc = ((E + SEB - 1) / SEB) * 8;
  const int gP2 = ((E + PEB - 1) / PEB) * 8;

  // 0. index-width detect + zero cum
  k_detect_i64<<<1, TPB, 0, stream>>>((const unsigned int*)ei, E, flag, cum);
  // 1. chunk counts -> bases; zero sub-bucket counts
  k_count8<<<512, TPB, 0, stream>>>(ei, flag, cum, E, Nc);
  k_cbase<<<1, 64, 0, stream>>>(cum, ccnt, cbase, gtail, E);
  k_zero_i<<<(NSB + TPB - 1) / TPB, TPB, 0, stream>>>(scnt, NSB);
  // 2. level-1 bucket (ballot-aggregated)
  k_bucket<<<gBk, TPB, 0, stream>>>(ei, flag, gtail, pairW, E, Nc);
  // 3. sub-bucket counts -> bases
  k_scnt<<<gSc, TPB, 0, stream>>>(cbase, ccnt, pairR, scnt, nsb_c, Nc);
  k_sbase<<<1, 1024, 0, stream>>>(scnt, sbase, stail, NSB);
  // 4. level-2 place: packed pair2, sub-bucket-grouped
  k_place2<<<gP2, TPB, 0, stream>>>(cbase, ccnt, pairW, stail, pair2, nsb_c, Nc);
  // 5. prep: deg -> dinv, gx = x*dinv
  k_prep<<<NSB, TPG, 0, stream>>>(scnt, sbase, pair2, x, dinv, gx, nsb_c, Nc, N);
  // 6. layer 1: fused sort+gather (16ch), transform
  k_gatherF<16><<<NSB, TPG, 0, stream>>>(scnt, sbase, pair2, dinv, gx, agg1, nsb_c, Nc, N);
  k_transform<16, 32, true, true><<<gN, TPB, 0, stream>>>(agg1, W1, b1, dinv, gh, N);
  // 7. layer 2: fused sort+gather (32ch), transform -> out
  k_gatherF<32><<<NSB, TPG, 0, stream>>>(scnt, sbase, pair2, dinv, gh, agg2, nsb_c, Nc, N);
  k_transform<32, 32, false, false><<<gN, TPB, 0, stream>>>(agg2, W2, b2, dinv, out, N);
}